// Round 8
// baseline (12912.619 us; speedup 1.0000x reference)
//
#include <hip/hip_runtime.h>
#include <math.h>

#define Bb     32
#define NVv    400
#define Mm     512
#define Kk     32
#define Nn     501
#define MAXIT  10
#define EPSd   1e-12f
#define NT     512
#define TW     32

typedef float v2f __attribute__((ext_vector_type(2)));

// DPP add-combine: x += dpp_perm(x). Lanes outside rmask add old=0.
#define DPP_ADD(x, ctrl, rmask)                                                        \
    (x) += __int_as_float(__builtin_amdgcn_update_dpp(                                 \
              0, __float_as_int(x), (ctrl), (rmask), 0xF, false))

#define QUAD_PERM_X1 0xB1   // xor-1
#define QUAD_PERM_X2 0x4E   // xor-2
#define ROW_HALF_MIR 0x141  // quad-exchange within 8 (quads uniform after xor1,2)
#define ROW_MIR      0x140  // 8-group exchange within 16 (8-uniform)

// 16-lane (row) sum: every lane of the row ends with its row total
#define REDUCE16(x)                 \
    DPP_ADD(x, QUAD_PERM_X1, 0xF);  \
    DPP_ADD(x, QUAD_PERM_X2, 0xF);  \
    DPP_ADD(x, ROW_HALF_MIR, 0xF);  \
    DPP_ADD(x, ROW_MIR,      0xF)

__global__ void __launch_bounds__(NT, 1)
satnet_kernel(const float* __restrict__ S, const float* __restrict__ z,
              const int* __restrict__ isin, const float* __restrict__ Vinit,
              const int* __restrict__ perm, float* __restrict__ out)
{
    __shared__ __align__(16) float V_lds[Nn * Kk];        // 64128 B
    __shared__ __align__(16) float P0_lds[TW * Kk];       // 4096 B: P0[j][k]
    __shared__ __align__(16) float GwT_lds[TW * TW];      // 4096 B: GwT[j][l]
    __shared__ __align__(16) float dv_lds[8 * Kk * 4];    // 4096 B: [l>>2][k][l&3]
    __shared__ int   idx_lds[TW];
    __shared__ float z_lds[Nn];
    __shared__ int   inp_lds[Nn];
    __shared__ float sn_lds[Nn];
    __shared__ int   permc[Nn - 1];
    __shared__ float v0_lds[Kk];
    __shared__ int   cnt_lds;

    const int b    = blockIdx.x;
    const int t    = threadIdx.x;
    const int lane = t & 63;
    const int w    = t >> 6;            // 8 waves
    const int g    = (lane >> 4) & 3;   // row in wave (0..3)
    const int c    = lane & 15;         // col in row  (0..15)
    const int kk   = (w << 2) + g;      // this row's k (0..31)
    const int mb   = c << 5;            // m base: 32 floats per lane
    const float PI_F = 3.14159274101257324f;

    // ---------- phase 0: z_full / inp / Snrms ----------
    if (t < Nn) {
        float zv; int iv;
        if (t == 0)        { zv = 1.f;                iv = 1; }
        else if (t <= NVv) { zv = z[b * NVv + t - 1]; iv = isin[b * NVv + t - 1]; }
        else               { zv = 0.f;                iv = 0; }
        z_lds[t]   = zv;
        inp_lds[t] = (iv > 0) ? 1 : 0;

        const float4* row = (const float4*)(S + (size_t)t * Mm);
        float a0 = 0.f, a1 = 0.f, a2 = 0.f, a3 = 0.f;
        #pragma unroll 4
        for (int j = 0; j < Mm / 4; ++j) {
            float4 v = row[j];
            a0 += v.x * v.x; a1 += v.y * v.y; a2 += v.z * v.z; a3 += v.w * v.w;
        }
        sn_lds[t] = (a0 + a1) + (a2 + a3);
    }
    __syncthreads();

    // ---------- phase 1: V normalize + pin ----------
    {
        const int r   = t >> 5;   // 0..15
        const int kk2 = t & 31;

        if (t < 32) {  // row 0 -> v0
            float v = Vinit[((size_t)b * Nn) * Kk + t];
            float q = v * v;
            q += __shfl_xor(q, 1, 32); q += __shfl_xor(q, 2, 32);
            q += __shfl_xor(q, 4, 32); q += __shfl_xor(q, 8, 32);
            q += __shfl_xor(q, 16, 32);
            float nv = v / fmaxf(sqrtf(q), EPSd);
            v0_lds[t] = nv;
            V_lds[t] = nv;
        }
        __syncthreads();
        float v0k = v0_lds[kk2];

        for (int it = 0; it < 32; ++it) {
            int n = 1 + it * 16 + r;
            if (n <= 500) {
                float v = Vinit[((size_t)b * Nn + n) * Kk + kk2];
                float q = v * v;
                q += __shfl_xor(q, 1, 32); q += __shfl_xor(q, 2, 32);
                q += __shfl_xor(q, 4, 32); q += __shfl_xor(q, 8, 32);
                q += __shfl_xor(q, 16, 32);
                float nv = v / fmaxf(sqrtf(q), EPSd);
                float res = nv;
                if (inp_lds[n]) {
                    float d = nv * v0k;
                    d += __shfl_xor(d, 1, 32); d += __shfl_xor(d, 2, 32);
                    d += __shfl_xor(d, 4, 32); d += __shfl_xor(d, 8, 32);
                    d += __shfl_xor(d, 16, 32);
                    float vp = nv - d * v0k;
                    float q2 = vp * vp;
                    q2 += __shfl_xor(q2, 1, 32); q2 += __shfl_xor(q2, 2, 32);
                    q2 += __shfl_xor(q2, 4, 32); q2 += __shfl_xor(q2, 8, 32);
                    q2 += __shfl_xor(q2, 16, 32);
                    vp = vp / fmaxf(sqrtf(q2), EPSd);
                    float ang = PI_F * z_lds[n];
                    res = -cosf(ang) * v0k + sinf(ang) * vp;
                }
                V_lds[n * Kk + kk2] = res;
            }
        }
    }
    __syncthreads();

    // ---------- phase 2 (wave 0): compact perm (pinned = exact no-ops) ----------
    if (w == 0) {
        int cc = 0;
        for (int base = 0; base < Nn - 1; base += 64) {
            int idx = base + lane;
            int iv = 0; bool keep = false;
            if (idx < Nn - 1) { iv = perm[idx]; keep = (inp_lds[iv] == 0); }
            unsigned long long mk = __ballot(keep);
            int pos = cc + (int)__popcll(mk & ((1ull << lane) - 1ull));
            if (keep) permc[pos] = iv;
            cc += (int)__popcll(mk);
        }
        if (lane == 0) cnt_lds = cc;
    }

    // ---------- phase 3 (all waves): W init, row layout ----------
    // wreg[2q],[2q+1] = W[kk][mb+4q .. mb+4q+3] as v2f pairs
    v2f wreg[16];
    #pragma unroll
    for (int q = 0; q < 16; ++q) wreg[q] = (v2f){0.f, 0.f};
    #pragma unroll 2
    for (int n = 0; n < Nn; ++n) {
        float vk = V_lds[n * Kk + kk];   // row-uniform broadcast
        const float4* sp = (const float4*)(S + (size_t)n * Mm + mb);
        v2f vv = (v2f){vk, vk};
        #pragma unroll
        for (int q = 0; q < 8; ++q) {
            float4 x = sp[q];
            wreg[2*q]   += vv * (v2f){x.x, x.y};
            wreg[2*q+1] += vv * (v2f){x.z, x.w};
        }
    }
    __syncthreads();
    const int cnt   = cnt_lds;
    const int total = MAXIT * cnt;

    // ---------- main: window loop ----------
    for (int ts = 0; ts < total; ts += TW) {
        const int Tw = (total - ts < TW) ? (total - ts) : TW;

        // stage: window indices + zero dv history
        if (t < TW) {
            int r = (ts + t) % cnt;
            idx_lds[t] = permc[r];
        }
        dv_lds[t * 2]     = 0.f;
        dv_lds[t * 2 + 1] = 0.f;
        __syncthreads();

        // ---- slab + Gram (all waves): P0[j][k] = W·s_j ; GwT[j][l] = s_l·s_j ----
        {
            const int il = idx_lds[kk];
            const float4* slp = (const float4*)(S + (size_t)il * Mm + mb);
            v2f sl[16];
            #pragma unroll
            for (int q = 0; q < 8; ++q) {
                float4 x = slp[q];
                sl[2*q] = (v2f){x.x, x.y}; sl[2*q+1] = (v2f){x.z, x.w};
            }
            #pragma unroll 2
            for (int j = 0; j < TW; ++j) {
                const int ij = idx_lds[j];
                const float4* sjp = (const float4*)(S + (size_t)ij * Mm + mb);
                v2f sj[16];
                #pragma unroll
                for (int q = 0; q < 8; ++q) {
                    float4 x = sjp[q];
                    sj[2*q] = (v2f){x.x, x.y}; sj[2*q+1] = (v2f){x.z, x.w};
                }
                v2f pa = wreg[0] * sj[0], pb = wreg[1] * sj[1];
                v2f ga = sl[0]   * sj[0], gb = sl[1]   * sj[1];
                #pragma unroll
                for (int q = 2; q < 16; q += 2) {
                    pa += wreg[q] * sj[q]; pb += wreg[q+1] * sj[q+1];
                    ga += sl[q]   * sj[q]; gb += sl[q+1]   * sj[q+1];
                }
                float pv = (pa.x + pa.y) + (pb.x + pb.y);
                float gv = (ga.x + ga.y) + (gb.x + gb.y);
                REDUCE16(pv);
                REDUCE16(gv);
                if (c == 0) {
                    P0_lds [(j << 5) + kk] = pv;
                    GwT_lds[(j << 5) + kk] = gv;
                }
            }
        }
        __syncthreads();

        // ---- inner: wave 0 only, barrier-free sequential steps ----
        if (w == 0) {
            const int k = lane & 31;
            #pragma unroll 1
            for (int jj = 0; jj < Tw; ++jj) {
                const int i = idx_lds[jj];
                float p = P0_lds[(jj << 5) + k];
                v2f a0 = (v2f){0.f, 0.f}, a1 = (v2f){0.f, 0.f};
                #pragma unroll
                for (int l4 = 0; l4 < 8; ++l4) {
                    float4 dq = *(const float4*)&dv_lds[(l4 << 7) + (k << 2)];
                    float4 gq = *(const float4*)&GwT_lds[(jj << 5) + (l4 << 2)];
                    a0 += (v2f){dq.x, dq.y} * (v2f){gq.x, gq.y};
                    a1 += (v2f){dq.z, dq.w} * (v2f){gq.z, gq.w};
                }
                p += (a0.x + a0.y) + (a1.x + a1.y);
                const float sni  = sn_lds[i];
                const float vold = V_lds[i * Kk + k];
                const float gg   = fmaf(-sni, vold, p);
                float qv = gg * gg;
                DPP_ADD(qv, QUAD_PERM_X1, 0xF);
                DPP_ADD(qv, QUAD_PERM_X2, 0xF);
                DPP_ADD(qv, ROW_HALF_MIR, 0xF);
                DPP_ADD(qv, ROW_MIR,      0xF);
                qv += __shfl_xor(qv, 16, 64);
                const float rden = -1.0f / fmaxf(sqrtf(qv), EPSd);
                const float vnew = gg * rden;
                const float dvv  = vnew - vold;
                V_lds[i * Kk + k] = vnew;                            // dup upper lanes: same addr+data
                dv_lds[((jj >> 2) << 7) + (k << 2) + (jj & 3)] = dvv;
            }
        }
        __syncthreads();

        // ---- fold (all waves): W += sum_l dv_l (x) s_l  (dv=0 beyond Tw: exact) ----
        #pragma unroll 2
        for (int l = 0; l < TW; ++l) {
            const float dvl = dv_lds[((l >> 2) << 7) + (kk << 2) + (l & 3)];
            const int ilx = idx_lds[l];
            const float4* sp = (const float4*)(S + (size_t)ilx * Mm + mb);
            v2f dvv = (v2f){dvl, dvl};
            #pragma unroll
            for (int q = 0; q < 8; ++q) {
                float4 x = sp[q];
                wreg[2*q]   += dvv * (v2f){x.x, x.y};
                wreg[2*q+1] += dvv * (v2f){x.z, x.w};
            }
        }
        __syncthreads();
    }

    // ---------- final: z_out = arccos(clip(-V.v0))/pi ----------
    {
        const int r   = t >> 5;   // 0..15
        const int kk2 = t & 31;
        float v0k = v0_lds[kk2];
        const float c1 = (float)(1.0 - 1e-7);
        #pragma unroll 1
        for (int it = 0; it < 25; ++it) {
            int n = 1 + it * 16 + r;   // 1..400
            float d = V_lds[n * Kk + kk2] * v0k;
            d += __shfl_xor(d, 1, 32); d += __shfl_xor(d, 2, 32);
            d += __shfl_xor(d, 4, 32); d += __shfl_xor(d, 8, 32);
            d += __shfl_xor(d, 16, 32);
            if (kk2 == 0) {
                float x = -d;
                x = fminf(fmaxf(x, -c1), c1);
                float zo = acosf(x) / PI_F;
                if (inp_lds[n]) zo = z_lds[n];
                out[b * NVv + (n - 1)] = zo;
            }
        }
    }
}

extern "C" void kernel_launch(void* const* d_in, const int* in_sizes, int n_in,
                              void* d_out, int out_size, void* d_ws, size_t ws_size,
                              hipStream_t stream) {
    const float* S     = (const float*)d_in[0];
    const float* z     = (const float*)d_in[1];
    const int*   isin  = (const int*)d_in[2];
    const float* Vinit = (const float*)d_in[3];
    const int*   perm  = (const int*)d_in[4];
    float* outp = (float*)d_out;
    hipLaunchKernelGGL(satnet_kernel, dim3(Bb), dim3(NT), 0, stream,
                       S, z, isin, Vinit, perm, outp);
}

// Round 9
// 2892.913 us; speedup vs baseline: 4.4635x; 4.4635x over previous
//
#include <hip/hip_runtime.h>
#include <math.h>

#define Bb     32
#define NVv    400
#define Mm     512
#define Kk     32
#define Nn     501
#define MAXIT  10
#define EPSd   1e-12f
#define NT     256

typedef float v2f __attribute__((ext_vector_type(2)));

// DPP add-combine: x += dpp_perm(x). Lanes outside rmask add old=0.
#define DPP_ADD(x, ctrl, rmask)                                                        \
    (x) += __int_as_float(__builtin_amdgcn_update_dpp(                                 \
              0, __float_as_int(x), (ctrl), (rmask), 0xF, false))

#define QUAD_PERM_X1 0xB1   // xor-1
#define QUAD_PERM_X2 0x4E   // xor-2
#define ROW_HALF_MIR 0x141  // xor-4 (quads uniform)
#define ROW_MIR      0x140  // xor-8 (8-groups uniform)
#define ROW_BCAST15  0x142  // row r+1 += row r lane15
#define ROW_BCAST31  0x143  // rows 2,3 += lane31

// full 64-lane sum; total valid in lanes 48-63 (read with readlane 63)
#define REDUCE64(x)                 \
    DPP_ADD(x, QUAD_PERM_X1, 0xF);  \
    DPP_ADD(x, QUAD_PERM_X2, 0xF);  \
    DPP_ADD(x, ROW_HALF_MIR, 0xF);  \
    DPP_ADD(x, ROW_MIR,      0xF);  \
    DPP_ADD(x, ROW_BCAST15,  0xA);  \
    DPP_ADD(x, ROW_BCAST31,  0xC)

// lgkm-only barrier: orders LDS ops without draining the global prefetch.
#define BLOCK_SYNC_LDS()                                           \
    do {                                                           \
        asm volatile("s_waitcnt lgkmcnt(0)" ::: "memory");         \
        __builtin_amdgcn_s_barrier();                              \
        asm volatile("" ::: "memory");                             \
    } while (0)

__global__ void __launch_bounds__(NT, 1)
satnet_kernel(const float* __restrict__ S, const float* __restrict__ z,
              const int* __restrict__ isin, const float* __restrict__ Vinit,
              const int* __restrict__ perm, float* __restrict__ out)
{
    __shared__ __align__(16) float V_lds[Nn * Kk];   // 64128 B, slice [8w,8w+8) owned by wave w
    __shared__ float z_lds[Nn];
    __shared__ int   inp_lds[Nn];
    __shared__ float sn_lds[Nn];
    __shared__ int   permc[Nn - 1];
    __shared__ float v0_lds[Kk];
    __shared__ __align__(16) float qred[2][4];
    __shared__ int   cnt_lds;

    const int b    = blockIdx.x;
    const int t    = threadIdx.x;
    const int lane = t & 63;
    const int w    = t >> 6;          // 4 waves: wave w owns k in [8w, 8w+8)
    const int kb   = w << 3;
    const int mb   = lane << 3;       // lane owns m in [8c, 8c+8)
    const float PI_F = 3.14159274101257324f;

    // ---------- phase 0: z_full / inp / Snrms ----------
    for (int r = t; r < Nn; r += NT) {
        float zv; int iv;
        if (r == 0)        { zv = 1.f;                iv = 1; }
        else if (r <= NVv) { zv = z[b * NVv + r - 1]; iv = isin[b * NVv + r - 1]; }
        else               { zv = 0.f;                iv = 0; }
        z_lds[r]   = zv;
        inp_lds[r] = (iv > 0) ? 1 : 0;

        const float4* row = (const float4*)(S + (size_t)r * Mm);
        float a0 = 0.f, a1 = 0.f, a2 = 0.f, a3 = 0.f;
        #pragma unroll 4
        for (int j = 0; j < Mm / 4; ++j) {
            float4 v = row[j];
            a0 += v.x * v.x; a1 += v.y * v.y; a2 += v.z * v.z; a3 += v.w * v.w;
        }
        sn_lds[r] = (a0 + a1) + (a2 + a3);
    }
    __syncthreads();

    // ---------- phase 1: V normalize + pin ----------
    {
        const int r   = t >> 5;   // 0..7
        const int kk2 = t & 31;

        if (t < 32) {  // row 0 -> v0
            float v = Vinit[((size_t)b * Nn) * Kk + t];
            float q = v * v;
            q += __shfl_xor(q, 1, 32); q += __shfl_xor(q, 2, 32);
            q += __shfl_xor(q, 4, 32); q += __shfl_xor(q, 8, 32);
            q += __shfl_xor(q, 16, 32);
            float nv = v / fmaxf(sqrtf(q), EPSd);
            v0_lds[t] = nv;
            V_lds[t] = nv;
        }
        __syncthreads();
        float v0k = v0_lds[kk2];

        for (int it = 0; it < 63; ++it) {
            int n = 1 + it * 8 + r;
            if (n <= 500) {
                float v = Vinit[((size_t)b * Nn + n) * Kk + kk2];
                float q = v * v;
                q += __shfl_xor(q, 1, 32); q += __shfl_xor(q, 2, 32);
                q += __shfl_xor(q, 4, 32); q += __shfl_xor(q, 8, 32);
                q += __shfl_xor(q, 16, 32);
                float nv = v / fmaxf(sqrtf(q), EPSd);
                float res = nv;
                if (inp_lds[n]) {
                    float d = nv * v0k;
                    d += __shfl_xor(d, 1, 32); d += __shfl_xor(d, 2, 32);
                    d += __shfl_xor(d, 4, 32); d += __shfl_xor(d, 8, 32);
                    d += __shfl_xor(d, 16, 32);
                    float vp = nv - d * v0k;
                    float q2 = vp * vp;
                    q2 += __shfl_xor(q2, 1, 32); q2 += __shfl_xor(q2, 2, 32);
                    q2 += __shfl_xor(q2, 4, 32); q2 += __shfl_xor(q2, 8, 32);
                    q2 += __shfl_xor(q2, 16, 32);
                    vp = vp / fmaxf(sqrtf(q2), EPSd);
                    float ang = PI_F * z_lds[n];
                    res = -cosf(ang) * v0k + sinf(ang) * vp;
                }
                V_lds[n * Kk + kk2] = res;
            }
        }
    }
    __syncthreads();

    // ---------- phase 2 (wave 0): compact perm (pinned coords are exact no-ops) ----------
    if (w == 0) {
        int cc = 0;
        for (int base = 0; base < Nn - 1; base += 64) {
            int idx = base + lane;
            int iv = 0; bool keep = false;
            if (idx < Nn - 1) { iv = perm[idx]; keep = (inp_lds[iv] == 0); }
            unsigned long long mk = __ballot(keep);
            int pos = cc + (int)__popcll(mk & ((1ull << lane) - 1ull));
            if (keep) permc[pos] = iv;
            cc += (int)__popcll(mk);
        }
        if (lane == 0) cnt_lds = cc;
    }

    // ---------- phase 3 (all waves): W init ----------
    // w2[j][q] = W[kb+j][mb+2q, mb+2q+1], q<4 (8 m's per lane)
    v2f w2[8][4];
    #pragma unroll
    for (int j = 0; j < 8; ++j)
        #pragma unroll
        for (int q = 0; q < 4; ++q) w2[j][q] = (v2f){0.f, 0.f};

    #pragma unroll 2
    for (int n = 0; n < Nn; ++n) {
        float4 va = *(const float4*)&V_lds[n * Kk + kb];       // wave-uniform
        float4 vb = *(const float4*)&V_lds[n * Kk + kb + 4];
        float4 s0 = *(const float4*)&S[(size_t)n * Mm + mb];
        float4 s1 = *(const float4*)&S[(size_t)n * Mm + mb + 4];
        v2f s2[4] = { {s0.x, s0.y}, {s0.z, s0.w}, {s1.x, s1.y}, {s1.z, s1.w} };
        const float vk[8] = {va.x, va.y, va.z, va.w, vb.x, vb.y, vb.z, vb.w};
        #pragma unroll
        for (int j = 0; j < 8; ++j) {
            v2f vv = (v2f){vk[j], vk[j]};
            #pragma unroll
            for (int q = 0; q < 4; ++q) w2[j][q] += vv * s2[q];
        }
    }
    __syncthreads();
    const int cnt = cnt_lds;

    // ---------- main loop: 4 waves, one lgkm-barrier per step ----------
    if (cnt > 0) {
        int i   = permc[0];
        int in1 = (cnt > 1) ? permc[1] : i;
        int sip = (cnt > 2) ? 2 : 0;

        const float* srow = S + (size_t)i * Mm + mb;
        float4 sa0 = *(const float4*)(srow);
        float4 sa1 = *(const float4*)(srow + 4);
        float4 va0 = *(const float4*)&V_lds[i * Kk + kb];
        float4 va1 = *(const float4*)&V_lds[i * Kk + kb + 4];
        float  sni = sn_lds[i];

        const int total = MAXIT * cnt;
        #pragma unroll 2
        for (int step = 0; step < total; ++step) {
            const int in2 = permc[sip];
            sip = (sip + 1 == cnt) ? 0 : sip + 1;
            // prefetch next step's data (global loads stay in flight across barrier)
            const float* srn = S + (size_t)in1 * Mm + mb;
            float4 sp0 = *(const float4*)(srn);
            float4 sp1 = *(const float4*)(srn + 4);
            float4 vp0 = *(const float4*)&V_lds[in1 * Kk + kb];
            float4 vp1 = *(const float4*)&V_lds[in1 * Kk + kb + 4];
            float  snn = sn_lds[in1];

            v2f s2[4] = { {sa0.x, sa0.y}, {sa0.z, sa0.w}, {sa1.x, sa1.y}, {sa1.z, sa1.w} };

            // gemv: p[j] = W[kb+j][my 8 m's] . s  -> full-m wave reduce
            float p[8];
            #pragma unroll
            for (int j = 0; j < 8; ++j) {
                v2f acc = w2[j][0] * s2[0];
                acc += w2[j][1] * s2[1];
                acc += w2[j][2] * s2[2];
                acc += w2[j][3] * s2[3];
                p[j] = acc.x + acc.y;
                REDUCE64(p[j]);
            }
            const float vo[8] = {va0.x, va0.y, va0.z, va0.w, va1.x, va1.y, va1.z, va1.w};
            float g[8], q = 0.f;
            #pragma unroll
            for (int j = 0; j < 8; ++j) {
                float ps = __int_as_float(__builtin_amdgcn_readlane(__float_as_int(p[j]), 63));
                g[j] = fmaf(-sni, vo[j], ps);
                q    = fmaf(g[j], g[j], q);
            }
            const int par = step & 1;
            if (lane == 0) qred[par][w] = q;
            BLOCK_SYNC_LDS();

            float4 qv = *(const float4*)&qred[par][0];
            float gn2 = (qv.x + qv.y) + (qv.z + qv.w);
            float gc  = fmaxf(gn2, 1e-24f);   // sqrt(gc) >= 1e-12 == reference clamp
            float rr;
            asm("v_rsq_f32 %0, %1" : "=v"(rr) : "v"(gc));
            rr = rr * fmaf(-0.5f * gc * rr, rr, 1.5f);   // Newton -> ~1ulp
            float4 vna, vnb; float dv[8];
            vna.x = -g[0] * rr; vna.y = -g[1] * rr; vna.z = -g[2] * rr; vna.w = -g[3] * rr;
            vnb.x = -g[4] * rr; vnb.y = -g[5] * rr; vnb.z = -g[6] * rr; vnb.w = -g[7] * rr;
            dv[0] = vna.x - vo[0]; dv[1] = vna.y - vo[1];
            dv[2] = vna.z - vo[2]; dv[3] = vna.w - vo[3];
            dv[4] = vnb.x - vo[4]; dv[5] = vnb.y - vo[5];
            dv[6] = vnb.z - vo[6]; dv[7] = vnb.w - vo[7];
            if (lane == 0) {
                *(float4*)&V_lds[i * Kk + kb]     = vna;
                *(float4*)&V_lds[i * Kk + kb + 4] = vnb;
            }
            #pragma unroll
            for (int j = 0; j < 8; ++j) {
                v2f dj = (v2f){dv[j], dv[j]};
                #pragma unroll
                for (int qq = 0; qq < 4; ++qq) w2[j][qq] += dj * s2[qq];
            }
            if (cnt == 1) { va0 = vna; va1 = vnb; }   // prefetched V[i] was stale
            else          { va0 = vp0; va1 = vp1; }
            sa0 = sp0; sa1 = sp1; sni = snn;
            i = in1; in1 = in2;
        }
    }
    __syncthreads();

    // ---------- final: z_out = arccos(clip(-V.v0))/pi ----------
    {
        const int r   = t >> 5;   // 0..7
        const int kk2 = t & 31;
        float v0k = v0_lds[kk2];
        const float c1 = (float)(1.0 - 1e-7);
        #pragma unroll 1
        for (int it = 0; it < 50; ++it) {
            int n = 1 + it * 8 + r;   // 1..400
            float d = V_lds[n * Kk + kk2] * v0k;
            d += __shfl_xor(d, 1, 32); d += __shfl_xor(d, 2, 32);
            d += __shfl_xor(d, 4, 32); d += __shfl_xor(d, 8, 32);
            d += __shfl_xor(d, 16, 32);
            if (kk2 == 0) {
                float x = -d;
                x = fminf(fmaxf(x, -c1), c1);
                float zo = acosf(x) / PI_F;
                if (inp_lds[n]) zo = z_lds[n];
                out[b * NVv + (n - 1)] = zo;
            }
        }
    }
}

extern "C" void kernel_launch(void* const* d_in, const int* in_sizes, int n_in,
                              void* d_out, int out_size, void* d_ws, size_t ws_size,
                              hipStream_t stream) {
    const float* S     = (const float*)d_in[0];
    const float* z     = (const float*)d_in[1];
    const int*   isin  = (const int*)d_in[2];
    const float* Vinit = (const float*)d_in[3];
    const int*   perm  = (const int*)d_in[4];
    float* outp = (float*)d_out;
    hipLaunchKernelGGL(satnet_kernel, dim3(Bb), dim3(NT), 0, stream,
                       S, z, isin, Vinit, perm, outp);
}